// Round 6
// baseline (269.489 us; speedup 1.0000x reference)
//
#include <hip/hip_runtime.h>

// ---------------- problem constants ----------------
#define B_     8192
#define D_     32
#define H_     128
#define PH_    64
#define PREP_  10
#define CS_    8
#define CH_    32
#define NT_    16
#define NO_    4096
#define NPOST_ 4
#define DT_    0.1f
#define TWO_LOGC 1.8378770664093453f   // 2*log(sqrt(2*pi))

// ---------------- bf16 fragment-blob offsets (ushort elements) ----------------
// blob layout for a KxN weight: element ((kc*ntiles+nt)*64+lane)*8+j holds
// W[kc*32 + 4*((lane>>4)&3) + (j&3) + 16*(j>>2)][nt*16 + (lane&15)]
// Merged: XZXN = [xz_w | xn_w] (64x256), WIH = w_ih (320x384), WHH = w_hh (128x384).
#define OFF_XZXN 0        // 64x256   -> 16384
#define OFF_HZ   16384    // 128x128  -> 16384
#define OFF_HN   32768    // 128x128  -> 16384
#define OFF_PW1  49152    // 128x64   -> 8192
#define OFF_PW2  57344    // 64x64    -> 4096
#define OFF_WIH  61440    // 320x384  -> 122880
#define OFF_WHH  184320   // 128x384  -> 49152
#define BLOB_ELEMS 233472
#define INV_BYTE_OFF ((size_t)BLOB_ELEMS*2)

// activation LDS strides (ushorts): stride_dw % 32 == 4 -> worst 2-way (free)
#define STRH 136
#define STRP 72
#define STRG 328
#define PFSTR 67          // fp32 p stride (floats)

// shared fp32 constant table offsets (floats)
#define SB_XZ    0
#define SB_XN    128
#define SB_P1    256
#define SB_P2    320
#define SB_BRZ   384      // b_ih+b_hh for r (0..127) and z (128..255)
#define SB_BIN   640      // b_ih n-chunk
#define SB_BHN   768      // b_hh n-chunk
#define SB_WPREP 896      // 1280
#define SB_BPREP 2176     // 320
#define SB_TOT   2496

typedef float f4  __attribute__((ext_vector_type(4)));
typedef short bf8 __attribute__((ext_vector_type(8)));

__device__ __forceinline__ f4 mfma16(bf8 a, bf8 b, f4 c){
  return __builtin_amdgcn_mfma_f32_16x16x32_bf16(a,b,c,0,0,0);
}
__device__ __forceinline__ unsigned short f2bf(float f){
  unsigned int u = __builtin_bit_cast(unsigned int, f);
  u = (u + 0x7FFFu + ((u>>16)&1u)) >> 16;
  return (unsigned short)u;
}
__device__ __forceinline__ float sigmoidf_(float x){ return 1.f/(1.f+__expf(-x)); }
// column k -> ushort position inside a swizzled activation row (fragment order)
__device__ __forceinline__ int permk(int k){
  return ((k>>5)<<5) | (((k>>2)&3)<<3) | (((k>>4)&1)<<2) | (k&3);
}

// Wave-sliced GEMM slice: 16 rows (one row-tile, base folded into Ald), wave
// owns col tiles {tile0 + s*8 : s<NSEL} of an NTT-tile-wide fragment blob.
// A from swizzled LDS (1 ds_read_b128 per kc), B streamed from L2 blob.
// unroll 2 caps the in-flight load window (anti-spill; R2/R3 lesson).
template<int NKC,int NSEL,int NTT>
__device__ __forceinline__ void gemmW(f4 (&acc)[NSEL], const unsigned short* Ald,
                                      int strideUsh, const unsigned short* __restrict__ Bg,
                                      int lane, int tile0){
  const int lc = lane & 15, a4 = lane >> 4;
  const unsigned short* a0 = Ald + lc*strideUsh + a4*8;
  const unsigned short* bl = Bg + (size_t)tile0*512 + lane*8;
  #pragma unroll 2
  for(int kc=0;kc<NKC;kc++){
    bf8 av0 = *(const bf8*)(a0 + kc*32);
    #pragma unroll
    for(int s=0;s<NSEL;s++){
      bf8 bv = *(const bf8*)(bl + (size_t)(kc*NTT + s*8)*512);
      acc[s] = mfma16(av0, bv, acc[s]);
    }
  }
}

// ---------------- prep kernels ----------------
__global__ void init_inv(unsigned short* inv, float* outLoss){
  int i = blockIdx.x*256 + threadIdx.x;
  if(i < NT_*B_) inv[i] = 0xFFFFu;
  if(i == 0) *outLoss = 0.f;
}

__global__ void scatter_inv(unsigned short* inv, const int* __restrict__ obs){
  int i = blockIdx.x*256 + threadIdx.x;
  if(i < NT_*NO_){
    int t = i >> 12;
    int o = i & 4095;
    inv[(size_t)t*B_ + obs[i]] = (unsigned short)o;
  }
}

__global__ void build_blobs(const float* __restrict__ pw1, const float* __restrict__ pw2,
                            const float* __restrict__ xzw, const float* __restrict__ xnw,
                            const float* __restrict__ hzw, const float* __restrict__ hnw,
                            const float* __restrict__ wih, const float* __restrict__ whh,
                            unsigned short* __restrict__ blob){
  int sec = blockIdx.y;
  int e = blockIdx.x*256 + threadIdx.x;
  const float* src=nullptr; int N, ld, off, cnt;
  switch(sec){
    case 0: src=nullptr; N=256; ld=0;   off=OFF_XZXN; cnt=16384;  break; // [xz|xn]
    case 1: src=hzw;  N=128; ld=128; off=OFF_HZ;   cnt=16384;  break;
    case 2: src=hnw;  N=128; ld=128; off=OFF_HN;   cnt=16384;  break;
    case 3: src=pw1;  N=64;  ld=64;  off=OFF_PW1;  cnt=8192;   break;
    case 4: src=pw2;  N=64;  ld=64;  off=OFF_PW2;  cnt=4096;   break;
    case 5: src=wih;  N=384; ld=384; off=OFF_WIH;  cnt=122880; break;
    default:src=whh;  N=384; ld=384; off=OFF_WHH;  cnt=49152;  break;
  }
  if(e >= cnt) return;
  int ntiles = N >> 4;
  int perkc = ntiles << 9;
  int kc = e / perkc, rem = e % perkc;
  int nt = rem >> 9, li = rem & 511;
  int lane = li >> 3, j = li & 7;
  int n = nt*16 + (lane & 15);
  int k = kc*32 + ((lane>>4)&3)*4 + (j&3) + ((j>>2)<<4);
  float v;
  if(sec==0) v = (n<128) ? xzw[(size_t)k*128+n] : xnw[(size_t)k*128 + (n-128)];
  else       v = src[(size_t)k*ld + n];
  blob[off + e] = f2bf(v);
}

// ---------------- fused persistent kernel ----------------
// 256 blocks x 1024 threads (16 waves = 4 waves/SIMD); 32 rows/block.
// Wave w: rw=w&1 (row-tile), cw=w>>1 (16-col slice). Row-wave pairs read the
// same B tiles in the same phase -> L1 catches the duplicate stream.
__global__ __launch_bounds__(1024,4) void fused(
    const float* __restrict__ X, const float* __restrict__ M,
    const float* __restrict__ cov,
    const float* __restrict__ cm_w1, const float* __restrict__ cm_b1,
    const float* __restrict__ cm_w2, const float* __restrict__ cm_b2,
    const float* __restrict__ p_b1, const float* __restrict__ p_b2,
    const float* __restrict__ xz_b, const float* __restrict__ xn_b,
    const float* __restrict__ b_ih, const float* __restrict__ b_hh,
    const float* __restrict__ w_prep, const float* __restrict__ bias_prep,
    const unsigned short* __restrict__ blob, const unsigned short* __restrict__ inv,
    float* __restrict__ outH, float* __restrict__ outP, float* __restrict__ outLoss)
{
  __shared__ __align__(16) unsigned short hb[32*STRH];   // bf16 h (swizzled)
  __shared__ __align__(16) unsigned short pb[32*STRP];   // bf16 p
  __shared__ __align__(16) unsigned short un[32*STRG];   // union: qb / zh / gin
  __shared__ __align__(16) float pf32[32*PFSTR];         // fp32 p
  __shared__ float sb[SB_TOT];
  __shared__ int obsO[32];
  __shared__ float lred[16];

  const int tid  = threadIdx.x;
  const int lane = tid & 63;
  const int w    = tid >> 6;           // wave 0..15
  const int rw   = w & 1;              // row-tile
  const int cw   = w >> 1;             // col slice 0..7
  const int lc   = lane & 15;
  const int a4   = lane >> 4;          // 0..3
  const int base = blockIdx.x * 32;
  float lsum = 0.f;

  // ---- stage fp32 constants ----
  for(int i=tid;i<128;i+=1024){ sb[SB_XZ+i]=xz_b[i]; sb[SB_XN+i]=xn_b[i];
                                sb[SB_BIN+i]=b_ih[256+i]; sb[SB_BHN+i]=b_hh[256+i]; }
  for(int i=tid;i<64;i+=1024){ sb[SB_P1+i]=p_b1[i]; sb[SB_P2+i]=p_b2[i]; }
  for(int i=tid;i<256;i+=1024) sb[SB_BRZ+i]=b_ih[i]+b_hh[i];
  for(int i=tid;i<1280;i+=1024) sb[SB_WPREP+i]=w_prep[i];
  for(int i=tid;i<320;i+=1024) sb[SB_BPREP+i]=bias_prep[i];

  // ---- init h = tanh(relu(cov@cm_w1+b1)@cm_w2+b2) (one-time scalar path) ----
  {
    float* c1f = pf32;                  // [32][36] scratch
    float* hInitF = (float*)un;         // [32][132] scratch
    int row = tid>>5, q = tid&31;       // 32 rows x 32 cols
    float a = cm_b1[q];
    #pragma unroll
    for(int k=0;k<CS_;k++)
      a += cov[(size_t)(base+row)*CS_+k]*cm_w1[k*CH_+q];
    c1f[row*36+q] = fmaxf(a,0.f);
    __syncthreads();
    float acc2[4];
    #pragma unroll
    for(int j=0;j<4;j++) acc2[j]=cm_b2[q*4+j];
    for(int k=0;k<CH_;k++){
      float cv = c1f[row*36+k];
      #pragma unroll
      for(int j=0;j<4;j++) acc2[j] += cv*cm_w2[k*H_+q*4+j];
    }
    #pragma unroll
    for(int j=0;j<4;j++) hInitF[row*132+q*4+j] = tanhf(acc2[j]);
    __syncthreads();
  }

  f4 hFr;           // h rows rw*16+a4*4+g, col cw*16+lc
  f4 pFr;           // (rw==0 waves) p rows prt*16+a4*4+g, col pct*16+lc
  const int prt = cw & 1, pct = cw >> 1;
  {
    float* hInitF = (float*)un;
    #pragma unroll
    for(int g=0;g<4;g++)
      hFr[g] = hInitF[(rw*16+a4*4+g)*132 + cw*16+lc];
    __syncthreads();                    // reads done before un reuse / hb write
    #pragma unroll
    for(int g=0;g<4;g++)
      hb[(rw*16+a4*4+g)*STRH + permk(cw*16+lc)] = f2bf(hFr[g]);
    __syncthreads();
  }

  // ---- p_model: rw==0 waves only (8 sub-tiles); rw==1 waves idle at barriers ----
  auto pmodel = [&](){
    f4 acc[1];
    if(rw==0){
      { float bv = sb[SB_P1 + pct*16+lc]; f4 t={bv,bv,bv,bv}; acc[0]=t; }
      gemmW<4,1,4>(acc, hb + prt*16*STRH, STRH, blob+OFF_PW1, lane, pct);
      #pragma unroll
      for(int g=0;g<4;g++)
        un[(prt*16+a4*4+g)*STRP + permk(pct*16+lc)] = f2bf(fmaxf(acc[0][g],0.f));
    }
    __syncthreads();
    if(rw==0){
      { float bv = sb[SB_P2 + pct*16+lc]; f4 t={bv,bv,bv,bv}; acc[0]=t; }
      gemmW<2,1,4>(acc, un + prt*16*STRP, STRP, blob+OFF_PW2, lane, pct);
      pFr = acc[0];
      #pragma unroll
      for(int g=0;g<4;g++){
        int row = prt*16+a4*4+g, col = pct*16+lc;
        float v = acc[0][g];
        pb[row*STRP + permk(col)] = f2bf(v);
        pf32[row*PFSTR + col] = v;
      }
    }
    __syncthreads();
  };

  // ---- euler: h += DT*(1-z)*(n-h) ----
  auto euler = [&](){
    f4 ax[2];   // [0]=xz part, [1]=xn part (merged 256-wide blob)
    { float bz = sb[SB_XZ + cw*16+lc], bn = sb[SB_XN + cw*16+lc];
      f4 tz={bz,bz,bz,bz}, tn={bn,bn,bn,bn}; ax[0]=tz; ax[1]=tn; }
    gemmW<2,2,16>(ax, pb + rw*16*STRP, STRP, blob+OFF_XZXN, lane, cw);
    f4 ah[1]; { f4 z4={0.f,0.f,0.f,0.f}; ah[0]=z4; }
    gemmW<4,1,8>(ah, hb + rw*16*STRH, STRH, blob+OFF_HZ, lane, cw);
    f4 zr;
    #pragma unroll
    for(int g=0;g<4;g++){
      float z = sigmoidf_(ax[0][g] + ah[0][g]);
      zr[g]=z;
      un[(rw*16+a4*4+g)*STRH + permk(cw*16+lc)] = f2bf(z*hFr[g]);   // zh
    }
    __syncthreads();
    { f4 z4={0.f,0.f,0.f,0.f}; ah[0]=z4; }
    gemmW<4,1,8>(ah, un + rw*16*STRH, STRH, blob+OFF_HN, lane, cw);
    #pragma unroll
    for(int g=0;g<4;g++){
      float nn = tanhf(ax[1][g] + ah[0][g]);
      float ho = hFr[g];
      float hv = ho + DT_*(1.f-zr[g])*(nn-ho);
      hFr[g]=hv;
      hb[(rw*16+a4*4+g)*STRH + permk(cw*16+lc)] = f2bf(hv);
    }
    __syncthreads();
  };

  // ---- Bayesian jump: merged-gate GEMMs (tiles {cw, cw+8, cw+16} of 384) ----
  auto jump = [&](int t){
    { // gin + loss + obsO publication in one phase: thread -> (row=tid>>5, d=tid&31)
      int row = tid>>5, d = tid&31;
      unsigned short v = inv[(size_t)t*B_ + base + row];
      int o = (v==0xFFFFu)? -1 : (int)v;
      if(d==0) obsO[row] = o;
      float xa=0.f, ma=0.f;
      if(o>=0){
        xa = X[((size_t)t*NO_+o)*D_ + d];
        ma = M[((size_t)t*NO_+o)*D_ + d];
      }
      float mean = pf32[row*PFSTR + d];
      float lv   = pf32[row*PFSTR + D_ + d];
      float sg = __expf(0.5f*lv);
      float er = (xa-mean)/sg;
      if(ma>0.f) lsum += 0.5f*(er*er + lv + TWO_LOGC);
      const float* wp  = sb + SB_WPREP + d*4*PREP_;
      const float* bpv = sb + SB_BPREP + d*PREP_;
      #pragma unroll
      for(int pr=0;pr<PREP_;pr++){
        float s = xa*wp[pr] + mean*wp[PREP_+pr] + lv*wp[2*PREP_+pr] + er*wp[3*PREP_+pr] + bpv[pr];
        s = fmaxf(s,0.f);
        un[row*STRG + permk(d*PREP_+pr)] = f2bf((ma>0.f)? s : 0.f);  // gin
      }
    }
    __syncthreads();
    // gi = gin @ [wih_r|wih_z|wih_n] (+biases); gh = h @ [whh_r|whh_z|whh_n]
    f4 gi[3];
    { float br = sb[SB_BRZ + cw*16+lc], bz = sb[SB_BRZ+128 + cw*16+lc], bn = sb[SB_BIN + cw*16+lc];
      f4 tr={br,br,br,br}, tz={bz,bz,bz,bz}, tn={bn,bn,bn,bn};
      gi[0]=tr; gi[1]=tz; gi[2]=tn; }
    gemmW<10,3,24>(gi, un + rw*16*STRG, STRG, blob+OFF_WIH, lane, cw);
    f4 gh[3];
    { float bhn = sb[SB_BHN + cw*16+lc];
      f4 z4={0.f,0.f,0.f,0.f}, tn={bhn,bhn,bhn,bhn};
      gh[0]=z4; gh[1]=z4; gh[2]=tn; }
    gemmW<4,3,24>(gh, hb + rw*16*STRH, STRH, blob+OFF_WHH, lane, cw);
    __syncthreads();   // all waves done reading hb/un before conditional hb writes
    #pragma unroll
    for(int g=0;g<4;g++){
      int row = rw*16+a4*4+g;
      float r = sigmoidf_(gi[0][g] + gh[0][g]);
      float z = sigmoidf_(gi[1][g] + gh[1][g]);
      float nn = tanhf(gi[2][g] + r*gh[2][g]);
      float hv = (1.f-z)*nn + z*hFr[g];
      if(obsO[row]>=0){
        hFr[g]=hv;
        hb[row*STRH + permk(cw*16+lc)] = f2bf(hv);
      }
    }
    __syncthreads();
  };

  // ---- sequence ----
  pmodel();
  for(int t=0;t<NT_;t++){
    euler();
    pmodel();
    jump(t);
    pmodel();
  }
  for(int it=0;it<NPOST_;it++){
    euler();
    pmodel();
  }

  // ---- outputs ----
  #pragma unroll
  for(int g=0;g<4;g++)
    outH[(size_t)(base + rw*16+a4*4+g)*H_ + cw*16+lc] = hFr[g];
  if(rw==0){
    #pragma unroll
    for(int g=0;g<4;g++)
      outP[(size_t)(base + prt*16+a4*4+g)*(2*D_) + pct*16+lc] = pFr[g];
  }

  #pragma unroll
  for(int off=32;off>0;off>>=1) lsum += __shfl_down(lsum, off);
  if(lane==0) lred[w]=lsum;
  __syncthreads();
  if(tid==0){
    float s = 0.f;
    #pragma unroll
    for(int i=0;i<16;i++) s += lred[i];
    atomicAdd(outLoss, s);
  }
}

// ---------------- launcher ----------------
extern "C" void kernel_launch(void* const* d_in, const int* in_sizes, int n_in,
                              void* d_out, int out_size, void* d_ws, size_t ws_size,
                              hipStream_t stream){
  const float* X      = (const float*)d_in[0];
  const float* M      = (const float*)d_in[1];
  const int*   obs    = (const int*)  d_in[2];
  const float* cov    = (const float*)d_in[3];
  const float* cm_w1  = (const float*)d_in[4];
  const float* cm_b1  = (const float*)d_in[5];
  const float* cm_w2  = (const float*)d_in[6];
  const float* cm_b2  = (const float*)d_in[7];
  const float* p_w1   = (const float*)d_in[8];
  const float* p_b1   = (const float*)d_in[9];
  const float* p_w2   = (const float*)d_in[10];
  const float* p_b2   = (const float*)d_in[11];
  const float* xz_w   = (const float*)d_in[12];
  const float* xz_b   = (const float*)d_in[13];
  const float* hz_w   = (const float*)d_in[14];
  const float* xn_w   = (const float*)d_in[15];
  const float* xn_b   = (const float*)d_in[16];
  const float* hn_w   = (const float*)d_in[17];
  const float* w_ih   = (const float*)d_in[18];
  const float* w_hh   = (const float*)d_in[19];
  const float* b_ih   = (const float*)d_in[20];
  const float* b_hh   = (const float*)d_in[21];
  const float* w_prep = (const float*)d_in[22];
  const float* bprep  = (const float*)d_in[23];

  unsigned short* blob = (unsigned short*)d_ws;
  unsigned short* inv  = (unsigned short*)((char*)d_ws + INV_BYTE_OFF);
  float* outH = (float*)d_out;
  float* outP = outH + (size_t)B_*H_;
  float* outLoss = outP + (size_t)B_*2*D_;

  init_inv   <<<dim3((NT_*B_+255)/256), dim3(256), 0, stream>>>(inv, outLoss);
  scatter_inv<<<dim3((NT_*NO_+255)/256), dim3(256), 0, stream>>>(inv, obs);
  build_blobs<<<dim3(480,7), dim3(256), 0, stream>>>(p_w1,p_w2,xz_w,xn_w,hz_w,hn_w,w_ih,w_hh, blob);
  fused      <<<dim3(B_/32), dim3(1024), 0, stream>>>(
      X, M, cov, cm_w1, cm_b1, cm_w2, cm_b2, p_b1, p_b2, xz_b, xn_b,
      b_ih, b_hh, w_prep, bprep, blob, inv, outH, outP, outLoss);
}

// Round 7
// 269.122 us; speedup vs baseline: 1.0014x; 1.0014x over previous
//
#include <hip/hip_runtime.h>

// ---------------- problem constants ----------------
#define B_     8192
#define D_     32
#define H_     128
#define PH_    64
#define PREP_  10
#define CS_    8
#define CH_    32
#define NT_    16
#define NO_    4096
#define NPOST_ 4
#define DT_    0.1f
#define TWO_LOGC 1.8378770664093453f   // 2*log(sqrt(2*pi))

// ---------------- bf16 fragment-blob offsets (ushort elements) ----------------
// blob layout for a KxN weight: element ((kc*ntiles+nt)*64+lane)*8+j holds
// W[kc*32 + 4*((lane>>4)&3) + (j&3) + 16*(j>>2)][nt*16 + (lane&15)]
// Merged: XZXN = [xz_w | xn_w] (64x256), WIH = w_ih (320x384), WHH = w_hh (128x384).
#define OFF_XZXN 0        // 64x256   -> 16384
#define OFF_HZ   16384    // 128x128  -> 16384
#define OFF_HN   32768    // 128x128  -> 16384
#define OFF_PW1  49152    // 128x64   -> 8192
#define OFF_PW2  57344    // 64x64    -> 4096
#define OFF_WIH  61440    // 320x384  -> 122880
#define OFF_WHH  184320   // 128x384  -> 49152
#define BLOB_ELEMS 233472
#define INV_BYTE_OFF ((size_t)BLOB_ELEMS*2)

// activation LDS strides (ushorts): stride_dw % 32 == 4 -> worst 2-way (free)
#define STRH 136
#define STRP 72
#define STRG 328
#define PFSTR 67          // fp32 p stride (floats)

// shared fp32 constant table offsets (floats)
#define SB_XZ    0
#define SB_XN    128
#define SB_P1    256
#define SB_P2    320
#define SB_BRZ   384      // b_ih+b_hh for r (0..127) and z (128..255)
#define SB_BIN   640      // b_ih n-chunk
#define SB_BHN   768      // b_hh n-chunk
#define SB_WPREP 896      // 1280
#define SB_BPREP 2176     // 320
#define SB_TOT   2496

typedef float f4  __attribute__((ext_vector_type(4)));
typedef short bf8 __attribute__((ext_vector_type(8)));

__device__ __forceinline__ f4 mfma16(bf8 a, bf8 b, f4 c){
  return __builtin_amdgcn_mfma_f32_16x16x32_bf16(a,b,c,0,0,0);
}
__device__ __forceinline__ unsigned short f2bf(float f){
  unsigned int u = __builtin_bit_cast(unsigned int, f);
  u = (u + 0x7FFFu + ((u>>16)&1u)) >> 16;
  return (unsigned short)u;
}
__device__ __forceinline__ float sigmoidf_(float x){ return 1.f/(1.f+__expf(-x)); }
// column k -> ushort position inside a swizzled activation row (fragment order)
__device__ __forceinline__ int permk(int k){
  return ((k>>5)<<5) | (((k>>2)&3)<<3) | (((k>>4)&1)<<2) | (k&3);
}

// Wave-sliced GEMM slice: 16 rows (one row-tile, base folded into Ald), wave
// owns col tiles {tile0 + s*8 : s<NSEL} of an NTT-tile-wide fragment blob.
// A from swizzled LDS (1 ds_read_b128 per kc), B streamed from L2 blob.
// unroll 2 caps the in-flight load window (anti-spill; R2/R3 lesson).
template<int NKC,int NSEL,int NTT>
__device__ __forceinline__ void gemmW(f4 (&acc)[NSEL], const unsigned short* Ald,
                                      int strideUsh, const unsigned short* __restrict__ Bg,
                                      int lane, int tile0){
  const int lc = lane & 15, a4 = lane >> 4;
  const unsigned short* a0 = Ald + lc*strideUsh + a4*8;
  const unsigned short* bl = Bg + (size_t)tile0*512 + lane*8;
  #pragma unroll 2
  for(int kc=0;kc<NKC;kc++){
    bf8 av0 = *(const bf8*)(a0 + kc*32);
    #pragma unroll
    for(int s=0;s<NSEL;s++){
      bf8 bv = *(const bf8*)(bl + (size_t)(kc*NTT + s*8)*512);
      acc[s] = mfma16(av0, bv, acc[s]);
    }
  }
}

// ---------------- prep kernels ----------------
__global__ void init_inv(unsigned short* inv, float* outLoss){
  int i = blockIdx.x*256 + threadIdx.x;
  if(i < NT_*B_) inv[i] = 0xFFFFu;
  if(i == 0) *outLoss = 0.f;
}

__global__ void scatter_inv(unsigned short* inv, const int* __restrict__ obs){
  int i = blockIdx.x*256 + threadIdx.x;
  if(i < NT_*NO_){
    int t = i >> 12;
    int o = i & 4095;
    inv[(size_t)t*B_ + obs[i]] = (unsigned short)o;
  }
}

__global__ void build_blobs(const float* __restrict__ pw1, const float* __restrict__ pw2,
                            const float* __restrict__ xzw, const float* __restrict__ xnw,
                            const float* __restrict__ hzw, const float* __restrict__ hnw,
                            const float* __restrict__ wih, const float* __restrict__ whh,
                            unsigned short* __restrict__ blob){
  int sec = blockIdx.y;
  int e = blockIdx.x*256 + threadIdx.x;
  const float* src=nullptr; int N, ld, off, cnt;
  switch(sec){
    case 0: src=nullptr; N=256; ld=0;   off=OFF_XZXN; cnt=16384;  break; // [xz|xn]
    case 1: src=hzw;  N=128; ld=128; off=OFF_HZ;   cnt=16384;  break;
    case 2: src=hnw;  N=128; ld=128; off=OFF_HN;   cnt=16384;  break;
    case 3: src=pw1;  N=64;  ld=64;  off=OFF_PW1;  cnt=8192;   break;
    case 4: src=pw2;  N=64;  ld=64;  off=OFF_PW2;  cnt=4096;   break;
    case 5: src=wih;  N=384; ld=384; off=OFF_WIH;  cnt=122880; break;
    default:src=whh;  N=384; ld=384; off=OFF_WHH;  cnt=49152;  break;
  }
  if(e >= cnt) return;
  int ntiles = N >> 4;
  int perkc = ntiles << 9;
  int kc = e / perkc, rem = e % perkc;
  int nt = rem >> 9, li = rem & 511;
  int lane = li >> 3, j = li & 7;
  int n = nt*16 + (lane & 15);
  int k = kc*32 + ((lane>>4)&3)*4 + (j&3) + ((j>>2)<<4);
  float v;
  if(sec==0) v = (n<128) ? xzw[(size_t)k*128+n] : xnw[(size_t)k*128 + (n-128)];
  else       v = src[(size_t)k*ld + n];
  blob[off + e] = f2bf(v);
}

// ---------------- fused persistent kernel ----------------
// 256 blocks x 1024 threads (16 waves = 4 waves/SIMD); 32 rows/block.
// Wave w: rw=w&1 (row-tile), cw=w>>1 (16-col slice). Row-wave pairs read the
// same B tiles in the same phase -> L1 catches the duplicate stream.
// __launch_bounds__(1024,1): a 16-wave block already forces <=128 VGPR for
// launchability; asking for more waves/EU (R6's ",4") made the compiler
// squeeze to 64 VGPR and spill ~60MB/call to scratch. Cap at the natural 128.
__global__ __launch_bounds__(1024,1) void fused(
    const float* __restrict__ X, const float* __restrict__ M,
    const float* __restrict__ cov,
    const float* __restrict__ cm_w1, const float* __restrict__ cm_b1,
    const float* __restrict__ cm_w2, const float* __restrict__ cm_b2,
    const float* __restrict__ p_b1, const float* __restrict__ p_b2,
    const float* __restrict__ xz_b, const float* __restrict__ xn_b,
    const float* __restrict__ b_ih, const float* __restrict__ b_hh,
    const float* __restrict__ w_prep, const float* __restrict__ bias_prep,
    const unsigned short* __restrict__ blob, const unsigned short* __restrict__ inv,
    float* __restrict__ outH, float* __restrict__ outP, float* __restrict__ outLoss)
{
  __shared__ __align__(16) unsigned short hb[32*STRH];   // bf16 h (swizzled)
  __shared__ __align__(16) unsigned short pb[32*STRP];   // bf16 p
  __shared__ __align__(16) unsigned short un[32*STRG];   // union: qb / zh / gin
  __shared__ __align__(16) float pf32[32*PFSTR];         // fp32 p
  __shared__ float sb[SB_TOT];
  __shared__ int obsO[32];
  __shared__ float lred[16];

  const int tid  = threadIdx.x;
  const int lane = tid & 63;
  const int w    = tid >> 6;           // wave 0..15
  const int rw   = w & 1;              // row-tile
  const int cw   = w >> 1;             // col slice 0..7
  const int lc   = lane & 15;
  const int a4   = lane >> 4;          // 0..3
  const int base = blockIdx.x * 32;
  float lsum = 0.f;

  // ---- stage fp32 constants ----
  for(int i=tid;i<128;i+=1024){ sb[SB_XZ+i]=xz_b[i]; sb[SB_XN+i]=xn_b[i];
                                sb[SB_BIN+i]=b_ih[256+i]; sb[SB_BHN+i]=b_hh[256+i]; }
  for(int i=tid;i<64;i+=1024){ sb[SB_P1+i]=p_b1[i]; sb[SB_P2+i]=p_b2[i]; }
  for(int i=tid;i<256;i+=1024) sb[SB_BRZ+i]=b_ih[i]+b_hh[i];
  for(int i=tid;i<1280;i+=1024) sb[SB_WPREP+i]=w_prep[i];
  for(int i=tid;i<320;i+=1024) sb[SB_BPREP+i]=bias_prep[i];

  // ---- init h = tanh(relu(cov@cm_w1+b1)@cm_w2+b2) (one-time scalar path) ----
  {
    float* c1f = pf32;                  // [32][36] scratch
    float* hInitF = (float*)un;         // [32][132] scratch
    int row = tid>>5, q = tid&31;       // 32 rows x 32 cols
    float a = cm_b1[q];
    #pragma unroll
    for(int k=0;k<CS_;k++)
      a += cov[(size_t)(base+row)*CS_+k]*cm_w1[k*CH_+q];
    c1f[row*36+q] = fmaxf(a,0.f);
    __syncthreads();
    float acc2[4];
    #pragma unroll
    for(int j=0;j<4;j++) acc2[j]=cm_b2[q*4+j];
    for(int k=0;k<CH_;k++){
      float cv = c1f[row*36+k];
      #pragma unroll
      for(int j=0;j<4;j++) acc2[j] += cv*cm_w2[k*H_+q*4+j];
    }
    #pragma unroll
    for(int j=0;j<4;j++) hInitF[row*132+q*4+j] = tanhf(acc2[j]);
    __syncthreads();
  }

  f4 hFr;           // h rows rw*16+a4*4+g, col cw*16+lc
  f4 pFr;           // (rw==0 waves) p rows prt*16+a4*4+g, col pct*16+lc
  const int prt = cw & 1, pct = cw >> 1;
  {
    float* hInitF = (float*)un;
    #pragma unroll
    for(int g=0;g<4;g++)
      hFr[g] = hInitF[(rw*16+a4*4+g)*132 + cw*16+lc];
    __syncthreads();                    // reads done before un reuse / hb write
    #pragma unroll
    for(int g=0;g<4;g++)
      hb[(rw*16+a4*4+g)*STRH + permk(cw*16+lc)] = f2bf(hFr[g]);
    __syncthreads();
  }

  // ---- p_model: rw==0 waves only (8 sub-tiles); rw==1 waves idle at barriers ----
  auto pmodel = [&](){
    f4 acc[1];
    if(rw==0){
      { float bv = sb[SB_P1 + pct*16+lc]; f4 t={bv,bv,bv,bv}; acc[0]=t; }
      gemmW<4,1,4>(acc, hb + prt*16*STRH, STRH, blob+OFF_PW1, lane, pct);
      #pragma unroll
      for(int g=0;g<4;g++)
        un[(prt*16+a4*4+g)*STRP + permk(pct*16+lc)] = f2bf(fmaxf(acc[0][g],0.f));
    }
    __syncthreads();
    if(rw==0){
      { float bv = sb[SB_P2 + pct*16+lc]; f4 t={bv,bv,bv,bv}; acc[0]=t; }
      gemmW<2,1,4>(acc, un + prt*16*STRP, STRP, blob+OFF_PW2, lane, pct);
      pFr = acc[0];
      #pragma unroll
      for(int g=0;g<4;g++){
        int row = prt*16+a4*4+g, col = pct*16+lc;
        float v = acc[0][g];
        pb[row*STRP + permk(col)] = f2bf(v);
        pf32[row*PFSTR + col] = v;
      }
    }
    __syncthreads();
  };

  // ---- euler: h += DT*(1-z)*(n-h) ----
  auto euler = [&](){
    f4 ax[2];   // [0]=xz part, [1]=xn part (merged 256-wide blob)
    { float bz = sb[SB_XZ + cw*16+lc], bn = sb[SB_XN + cw*16+lc];
      f4 tz={bz,bz,bz,bz}, tn={bn,bn,bn,bn}; ax[0]=tz; ax[1]=tn; }
    gemmW<2,2,16>(ax, pb + rw*16*STRP, STRP, blob+OFF_XZXN, lane, cw);
    f4 ah[1]; { f4 z4={0.f,0.f,0.f,0.f}; ah[0]=z4; }
    gemmW<4,1,8>(ah, hb + rw*16*STRH, STRH, blob+OFF_HZ, lane, cw);
    f4 zr;
    #pragma unroll
    for(int g=0;g<4;g++){
      float z = sigmoidf_(ax[0][g] + ah[0][g]);
      zr[g]=z;
      un[(rw*16+a4*4+g)*STRH + permk(cw*16+lc)] = f2bf(z*hFr[g]);   // zh
    }
    __syncthreads();
    { f4 z4={0.f,0.f,0.f,0.f}; ah[0]=z4; }
    gemmW<4,1,8>(ah, un + rw*16*STRH, STRH, blob+OFF_HN, lane, cw);
    #pragma unroll
    for(int g=0;g<4;g++){
      float nn = tanhf(ax[1][g] + ah[0][g]);
      float ho = hFr[g];
      float hv = ho + DT_*(1.f-zr[g])*(nn-ho);
      hFr[g]=hv;
      hb[(rw*16+a4*4+g)*STRH + permk(cw*16+lc)] = f2bf(hv);
    }
    __syncthreads();
  };

  // ---- Bayesian jump: merged-gate GEMMs (tiles {cw, cw+8, cw+16} of 384) ----
  auto jump = [&](int t){
    { // gin + loss + obsO publication in one phase: thread -> (row=tid>>5, d=tid&31)
      int row = tid>>5, d = tid&31;
      unsigned short v = inv[(size_t)t*B_ + base + row];
      int o = (v==0xFFFFu)? -1 : (int)v;
      if(d==0) obsO[row] = o;
      float xa=0.f, ma=0.f;
      if(o>=0){
        xa = X[((size_t)t*NO_+o)*D_ + d];
        ma = M[((size_t)t*NO_+o)*D_ + d];
      }
      float mean = pf32[row*PFSTR + d];
      float lv   = pf32[row*PFSTR + D_ + d];
      float sg = __expf(0.5f*lv);
      float er = (xa-mean)/sg;
      if(ma>0.f) lsum += 0.5f*(er*er + lv + TWO_LOGC);
      const float* wp  = sb + SB_WPREP + d*4*PREP_;
      const float* bpv = sb + SB_BPREP + d*PREP_;
      #pragma unroll
      for(int pr=0;pr<PREP_;pr++){
        float s = xa*wp[pr] + mean*wp[PREP_+pr] + lv*wp[2*PREP_+pr] + er*wp[3*PREP_+pr] + bpv[pr];
        s = fmaxf(s,0.f);
        un[row*STRG + permk(d*PREP_+pr)] = f2bf((ma>0.f)? s : 0.f);  // gin
      }
    }
    __syncthreads();
    // gi = gin @ [wih_r|wih_z|wih_n] (+biases); gh = h @ [whh_r|whh_z|whh_n]
    f4 gi[3];
    { float br = sb[SB_BRZ + cw*16+lc], bz = sb[SB_BRZ+128 + cw*16+lc], bn = sb[SB_BIN + cw*16+lc];
      f4 tr={br,br,br,br}, tz={bz,bz,bz,bz}, tn={bn,bn,bn,bn};
      gi[0]=tr; gi[1]=tz; gi[2]=tn; }
    gemmW<10,3,24>(gi, un + rw*16*STRG, STRG, blob+OFF_WIH, lane, cw);
    f4 gh[3];
    { float bhn = sb[SB_BHN + cw*16+lc];
      f4 z4={0.f,0.f,0.f,0.f}, tn={bhn,bhn,bhn,bhn};
      gh[0]=z4; gh[1]=z4; gh[2]=tn; }
    gemmW<4,3,24>(gh, hb + rw*16*STRH, STRH, blob+OFF_WHH, lane, cw);
    __syncthreads();   // all waves done reading hb/un before conditional hb writes
    #pragma unroll
    for(int g=0;g<4;g++){
      int row = rw*16+a4*4+g;
      float r = sigmoidf_(gi[0][g] + gh[0][g]);
      float z = sigmoidf_(gi[1][g] + gh[1][g]);
      float nn = tanhf(gi[2][g] + r*gh[2][g]);
      float hv = (1.f-z)*nn + z*hFr[g];
      if(obsO[row]>=0){
        hFr[g]=hv;
        hb[row*STRH + permk(cw*16+lc)] = f2bf(hv);
      }
    }
    __syncthreads();
  };

  // ---- sequence ----
  pmodel();
  for(int t=0;t<NT_;t++){
    euler();
    pmodel();
    jump(t);
    pmodel();
  }
  for(int it=0;it<NPOST_;it++){
    euler();
    pmodel();
  }

  // ---- outputs ----
  #pragma unroll
  for(int g=0;g<4;g++)
    outH[(size_t)(base + rw*16+a4*4+g)*H_ + cw*16+lc] = hFr[g];
  if(rw==0){
    #pragma unroll
    for(int g=0;g<4;g++)
      outP[(size_t)(base + prt*16+a4*4+g)*(2*D_) + pct*16+lc] = pFr[g];
  }

  #pragma unroll
  for(int off=32;off>0;off>>=1) lsum += __shfl_down(lsum, off);
  if(lane==0) lred[w]=lsum;
  __syncthreads();
  if(tid==0){
    float s = 0.f;
    #pragma unroll
    for(int i=0;i<16;i++) s += lred[i];
    atomicAdd(outLoss, s);
  }
}

// ---------------- launcher ----------------
extern "C" void kernel_launch(void* const* d_in, const int* in_sizes, int n_in,
                              void* d_out, int out_size, void* d_ws, size_t ws_size,
                              hipStream_t stream){
  const float* X      = (const float*)d_in[0];
  const float* M      = (const float*)d_in[1];
  const int*   obs    = (const int*)  d_in[2];
  const float* cov    = (const float*)d_in[3];
  const float* cm_w1  = (const float*)d_in[4];
  const float* cm_b1  = (const float*)d_in[5];
  const float* cm_w2  = (const float*)d_in[6];
  const float* cm_b2  = (const float*)d_in[7];
  const float* p_w1   = (const float*)d_in[8];
  const float* p_b1   = (const float*)d_in[9];
  const float* p_w2   = (const float*)d_in[10];
  const float* p_b2   = (const float*)d_in[11];
  const float* xz_w   = (const float*)d_in[12];
  const float* xz_b   = (const float*)d_in[13];
  const float* hz_w   = (const float*)d_in[14];
  const float* xn_w   = (const float*)d_in[15];
  const float* xn_b   = (const float*)d_in[16];
  const float* hn_w   = (const float*)d_in[17];
  const float* w_ih   = (const float*)d_in[18];
  const float* w_hh   = (const float*)d_in[19];
  const float* b_ih   = (const float*)d_in[20];
  const float* b_hh   = (const float*)d_in[21];
  const float* w_prep = (const float*)d_in[22];
  const float* bprep  = (const float*)d_in[23];

  unsigned short* blob = (unsigned short*)d_ws;
  unsigned short* inv  = (unsigned short*)((char*)d_ws + INV_BYTE_OFF);
  float* outH = (float*)d_out;
  float* outP = outH + (size_t)B_*H_;
  float* outLoss = outP + (size_t)B_*2*D_;

  init_inv   <<<dim3((NT_*B_+255)/256), dim3(256), 0, stream>>>(inv, outLoss);
  scatter_inv<<<dim3((NT_*NO_+255)/256), dim3(256), 0, stream>>>(inv, obs);
  build_blobs<<<dim3(480,7), dim3(256), 0, stream>>>(p_w1,p_w2,xz_w,xn_w,hz_w,hn_w,w_ih,w_hh, blob);
  fused      <<<dim3(B_/32), dim3(1024), 0, stream>>>(
      X, M, cov, cm_w1, cm_b1, cm_w2, cm_b2, p_b1, p_b2, xz_b, xn_b,
      b_ih, b_hh, w_prep, bprep, blob, inv, outH, outP, outLoss);
}